// Round 3
// baseline (261.020 us; speedup 1.0000x reference)
//
#include <hip/hip_runtime.h>
#include <hip/hip_bf16.h>
#include <stdint.h>

#define NROWS 32768
#define MCOLS 8192
#define DDIM  256

#define BM 128            // rows per (persistent) workgroup
#define BN 64             // cols per iteration
#define NT (MCOLS/BN)     // 128 iterations
#define NWG (NROWS/BM)    // 256 workgroups = 1 per CU

typedef __attribute__((ext_vector_type(8))) short short8_t;
typedef __attribute__((ext_vector_type(4))) float f32x4;

__device__ __forceinline__ unsigned short f2bf(float f) {
  uint32_t u = __float_as_uint(f);
  u += 0x7FFFu + ((u >> 16) & 1u);   // round-to-nearest-even
  return (unsigned short)(u >> 16);
}

// ---- K1: fused prep: bf16 convert X,Y; xhalf = 0.5||x||^2; cbuf = 0.5||y||^2 - psi
__global__ void k_prep(const float* __restrict__ X, const float* __restrict__ Y,
                       const float* __restrict__ psi,
                       unsigned short* __restrict__ Xb, unsigned short* __restrict__ Yb,
                       float* __restrict__ xhalf, float* __restrict__ cbuf,
                       float* __restrict__ sum_accum)
{
  const int lane = threadIdx.x & 63;
  const int gw = (blockIdx.x * blockDim.x + threadIdx.x) >> 6;
  const int nw = (gridDim.x * blockDim.x) >> 6;
  for (int row = gw; row < NROWS + MCOLS; row += nw) {
    const bool isX = row < NROWS;
    const int r = isX ? row : row - NROWS;
    const float* src = isX ? (X + (size_t)row * DDIM) : (Y + (size_t)r * DDIM);
    float4 v = ((const float4*)src)[lane];
    ushort4 o;
    o.x = f2bf(v.x); o.y = f2bf(v.y); o.z = f2bf(v.z); o.w = f2bf(v.w);
    if (isX) ((ushort4*)(Xb + (size_t)row * DDIM))[lane] = o;
    else     ((ushort4*)(Yb + (size_t)r   * DDIM))[lane] = o;
    float s = v.x*v.x + v.y*v.y + v.z*v.z + v.w*v.w;
    #pragma unroll
    for (int m = 32; m >= 1; m >>= 1) s += __shfl_xor(s, m);
    if (lane == 0) {
      if (isX) xhalf[row] = 0.5f * s;
      else     cbuf[r] = 0.5f * s - psi[r];
    }
  }
  if (blockIdx.x == 0 && threadIdx.x == 0) sum_accum[0] = 0.0f;
}

#define LOADB(dst, t_) do {                                                    \
    const char* _b = (const char*)Yb + (size_t)(t_) * 32768 + bcolOff;         \
    _Pragma("unroll") for (int _kf = 0; _kf < 8; ++_kf)                        \
      dst[_kf] = *(const short8_t*)(_b + _kf * 64);                            \
  } while (0)

#define COMPUTE(bX, t_) do {                                                   \
    const float cj = Cs[(t_) * 64 + wc * 16 + c15];                            \
    f32x4 acc[4];                                                              \
    __builtin_amdgcn_s_setprio(1);                                             \
    _Pragma("unroll") for (int _m = 0; _m < 4; ++_m)                           \
      acc[_m] = __builtin_amdgcn_mfma_f32_16x16x32_bf16(                       \
          a[_m][0], bX[0], (f32x4){0.f, 0.f, 0.f, 0.f}, 0, 0, 0);              \
    _Pragma("unroll") for (int _kf = 1; _kf < 8; ++_kf)                        \
      _Pragma("unroll") for (int _m = 0; _m < 4; ++_m)                         \
        acc[_m] = __builtin_amdgcn_mfma_f32_16x16x32_bf16(                     \
            a[_m][_kf], bX[_kf], acc[_m], 0, 0, 0);                            \
    __builtin_amdgcn_s_setprio(0);                                             \
    _Pragma("unroll") for (int _m = 0; _m < 4; ++_m) {                         \
      vmin[_m][0] = fminf(vmin[_m][0], cj - acc[_m][0]);                       \
      vmin[_m][1] = fminf(vmin[_m][1], cj - acc[_m][1]);                       \
      vmin[_m][2] = fminf(vmin[_m][2], cj - acc[_m][2]);                       \
      vmin[_m][3] = fminf(vmin[_m][3], cj - acc[_m][3]);                       \
    }                                                                          \
  } while (0)

// ---- K2: persistent-row MFMA sweep over N; A in registers; B global->reg
//          double-buffered; NO barriers in the main loop.
__global__ __launch_bounds__(512, 2) void k_gemm(
    const unsigned short* __restrict__ Xb, const unsigned short* __restrict__ Yb,
    const float* __restrict__ cbuf, const float* __restrict__ xhalf,
    float* __restrict__ sum_accum)
{
  __shared__ __align__(16) float Cs[MCOLS];        // 32 KiB: c[j] for all j
  __shared__ float Rmin[BM][4];                    // cross-wc merge (2 KiB)
  __shared__ float swave[8];

  const int brow = blockIdx.x * BM;
  const int tid  = threadIdx.x;
  const int wid  = tid >> 6;
  const int lane = tid & 63;
  const int wr = wid >> 2;          // 0..1 -> rows wr*64
  const int wc = wid & 3;           // 0..3 -> col strip wc*16 within BN
  const int c15 = lane & 15;
  const int w4  = lane >> 4;

  // A fragments -> registers (whole K): 32 x dwordx4 per lane
  short8_t a[4][8];
  {
    const char* aBase = (const char*)Xb + (size_t)(brow + wr * 64 + c15) * 512 + w4 * 16;
    #pragma unroll
    for (int m = 0; m < 4; ++m)
      #pragma unroll
      for (int kf = 0; kf < 8; ++kf)
        a[m][kf] = *(const short8_t*)(aBase + m * 8192 + kf * 64);
  }

  // stage c[] into LDS (4 rounds x 8 KiB, linear)
  #pragma unroll
  for (int g = 0; g < 4; ++g)
    __builtin_amdgcn_global_load_lds(
        (const __attribute__((address_space(1))) uint32_t*)((const char*)cbuf + (g * 512 + wid * 64 + lane) * 16),
        (__attribute__((address_space(3))) uint32_t*)((char*)Cs + (g * 512 + wid * 64) * 16),
        16, 0, 0);

  const int bcolOff = (wc * 16 + c15) * 512 + w4 * 16;

  short8_t bA[8], bB[8];
  LOADB(bA, 0);
  asm volatile("s_waitcnt vmcnt(0)" ::: "memory");
  __builtin_amdgcn_s_barrier();     // Cs ready (only barrier before epilogue)

  f32x4 vmin[4];
  #pragma unroll
  for (int m = 0; m < 4; ++m)
    vmin[m] = (f32x4){3.4e38f, 3.4e38f, 3.4e38f, 3.4e38f};

  #pragma unroll 1
  for (int t = 0; t < NT; t += 2) {
    LOADB(bB, t + 1);
    COMPUTE(bA, t);
    if (t + 2 < NT) LOADB(bA, t + 2);
    COMPUTE(bB, t + 1);
  }

  // ---- epilogue: min across the 16 lanes sharing (lane>>4) -> per-row per-wc min
  #pragma unroll
  for (int m = 0; m < 4; ++m)
    #pragma unroll
    for (int r = 0; r < 4; ++r) {
      float v = vmin[m][r];
      v = fminf(v, __shfl_xor(v, 1));
      v = fminf(v, __shfl_xor(v, 2));
      v = fminf(v, __shfl_xor(v, 4));
      v = fminf(v, __shfl_xor(v, 8));
      vmin[m][r] = v;
    }
  if (c15 == 0) {
    #pragma unroll
    for (int m = 0; m < 4; ++m)
      #pragma unroll
      for (int r = 0; r < 4; ++r)
        Rmin[wr * 64 + m * 16 + w4 * 4 + r][wc] = vmin[m][r];
  }
  __syncthreads();

  float s = 0.f;
  if (tid < BM) {
    const float v = fminf(fminf(Rmin[tid][0], Rmin[tid][1]),
                          fminf(Rmin[tid][2], Rmin[tid][3]));
    s = v + xhalf[brow + tid];
  }
  #pragma unroll
  for (int m = 32; m >= 1; m >>= 1) s += __shfl_xor(s, m);
  if (lane == 0) swave[wid] = s;
  __syncthreads();
  if (tid == 0) {
    float tot = swave[0] + swave[1] + swave[2] + swave[3]
              + swave[4] + swave[5] + swave[6] + swave[7];
    atomicAdd(sum_accum, tot);
  }
}

// ---- K3: out = sum/N + mean(psi)
__global__ void k_final(const float* __restrict__ psi, const float* __restrict__ sum_accum,
                        float* __restrict__ out)
{
  __shared__ float sh[4];
  float s = 0.f;
  for (int i = threadIdx.x; i < MCOLS; i += 256) s += psi[i];
  #pragma unroll
  for (int m = 32; m >= 1; m >>= 1) s += __shfl_xor(s, m);
  const int wid = threadIdx.x >> 6, lane = threadIdx.x & 63;
  if (lane == 0) sh[wid] = s;
  __syncthreads();
  if (threadIdx.x == 0)
    out[0] = sum_accum[0] / (float)NROWS + (sh[0] + sh[1] + sh[2] + sh[3]) / (float)MCOLS;
}

extern "C" void kernel_launch(void* const* d_in, const int* in_sizes, int n_in,
                              void* d_out, int out_size, void* d_ws, size_t ws_size,
                              hipStream_t stream)
{
  const float* X   = (const float*)d_in[0];
  const float* Y   = (const float*)d_in[1];
  const float* psi = (const float*)d_in[2];
  float* out = (float*)d_out;

  char* ws = (char*)d_ws;
  unsigned short* Xb = (unsigned short*)(ws);                                   // 16,777,216 B
  unsigned short* Yb = (unsigned short*)(ws + (size_t)NROWS * DDIM * 2);        //  4,194,304 B
  float* cbuf        = (float*)(ws + (size_t)(NROWS + MCOLS) * DDIM * 2);       //     32,768 B
  float* xhalf       = (float*)((char*)cbuf + (size_t)MCOLS * 4);               //    131,072 B
  float* sum_accum   = (float*)((char*)xhalf + (size_t)NROWS * 4);              //          4 B

  k_prep <<<2048, 256, 0, stream>>>(X, Y, psi, Xb, Yb, xhalf, cbuf, sum_accum);
  k_gemm <<<NWG, 512, 0, stream>>>(Xb, Yb, cbuf, xhalf, sum_accum);
  k_final<<<1, 256, 0, stream>>>(psi, sum_accum, out);
}

// Round 4
// 178.303 us; speedup vs baseline: 1.4639x; 1.4639x over previous
//
#include <hip/hip_runtime.h>
#include <hip/hip_bf16.h>
#include <stdint.h>

#define NROWS 32768
#define MCOLS 8192
#define DDIM  256

#define BM 128            // rows per (persistent) workgroup
#define BN 64             // cols per iteration
#define NT (MCOLS/BN)     // 128 iterations
#define NWG (NROWS/BM)    // 256 workgroups = 1 per CU

typedef __attribute__((ext_vector_type(8))) short short8_t;
typedef __attribute__((ext_vector_type(4))) float f32x4;

__device__ __forceinline__ unsigned short f2bf(float f) {
  uint32_t u = __float_as_uint(f);
  u += 0x7FFFu + ((u >> 16) & 1u);   // round-to-nearest-even
  return (unsigned short)(u >> 16);
}
// order-preserving float -> uint key (integer atomicMin == float min)
__device__ __forceinline__ uint32_t fkey(float f) {
  uint32_t b = __float_as_uint(f);
  return (b & 0x80000000u) ? ~b : (b | 0x80000000u);
}
__device__ __forceinline__ float funkey(uint32_t k) {
  uint32_t b = (k & 0x80000000u) ? (k ^ 0x80000000u) : ~k;
  return __uint_as_float(b);
}
__device__ __forceinline__ f32x4 vmin4(f32x4 x, f32x4 y) {
  f32x4 r;
  r[0] = fminf(x[0], y[0]); r[1] = fminf(x[1], y[1]);
  r[2] = fminf(x[2], y[2]); r[3] = fminf(x[3], y[3]);
  return r;
}

// ---- K1: fused prep: bf16 convert X,Y; xhalf = 0.5||x||^2; cbuf = 0.5||y||^2 - psi;
//          init rowkey; zero accumulator.
__global__ void k_prep(const float* __restrict__ X, const float* __restrict__ Y,
                       const float* __restrict__ psi,
                       unsigned short* __restrict__ Xb, unsigned short* __restrict__ Yb,
                       float* __restrict__ xhalf, float* __restrict__ cbuf,
                       uint32_t* __restrict__ rowkey, float* __restrict__ sum_accum)
{
  const int lane = threadIdx.x & 63;
  const int gw = (blockIdx.x * blockDim.x + threadIdx.x) >> 6;
  const int nw = (gridDim.x * blockDim.x) >> 6;
  for (int row = gw; row < NROWS + MCOLS; row += nw) {
    const bool isX = row < NROWS;
    const int r = isX ? row : row - NROWS;
    const float* src = isX ? (X + (size_t)row * DDIM) : (Y + (size_t)r * DDIM);
    float4 v = ((const float4*)src)[lane];
    ushort4 o;
    o.x = f2bf(v.x); o.y = f2bf(v.y); o.z = f2bf(v.z); o.w = f2bf(v.w);
    if (isX) ((ushort4*)(Xb + (size_t)row * DDIM))[lane] = o;
    else     ((ushort4*)(Yb + (size_t)r   * DDIM))[lane] = o;
    float s = v.x*v.x + v.y*v.y + v.z*v.z + v.w*v.w;
    #pragma unroll
    for (int m = 32; m >= 1; m >>= 1) s += __shfl_xor(s, m);
    if (lane == 0) {
      if (isX) { xhalf[row] = 0.5f * s; rowkey[row] = 0xFFFFFFFFu; }
      else     { cbuf[r] = 0.5f * s - psi[r]; }
    }
  }
  if (blockIdx.x == 0 && threadIdx.x == 0) sum_accum[0] = 0.0f;
}

// stage B tile for column-block t_ into ldsB half nb_ (64 rows x 512 B, XOR-swizzled
// source so the LINEAR global_load_lds dest + swizzled read form the same involution)
#define STAGEB(t_, nb_) do {                                                    \
    _Pragma("unroll") for (int _g = 0; _g < 4; ++_g) {                          \
      const int _row = _g * 16 + wid * 2 + (lane >> 5);                         \
      const char* _src = (const char*)Yb + (size_t)((t_) * 64 + _row) * 512     \
                         + (((lane & 31) << 4) ^ ((_row & 7) << 4));            \
      __builtin_amdgcn_global_load_lds(                                         \
          (const __attribute__((address_space(1))) uint32_t*)_src,              \
          (__attribute__((address_space(3))) uint32_t*)                         \
              (ldsB + (nb_) * 32768 + (_g * 16 + wid * 2) * 512), 16, 0, 0);    \
    }                                                                           \
  } while (0)

// read one swizzled B fragment: column group n_ (0/1), k-fragment kf_ (0..7)
#define RB(n_, kf_) (*(const short8_t*)(bRd + (n_) * 8192 +                     \
                      ((w4 * 16 + (kf_) * 64) ^ csw)))

// ---- K2: persistent-row MFMA sweep; A (32 rows x K=256 per wave) in registers;
//          B streamed through double-buffered swizzled LDS; 1 barrier/iter.
__global__ __launch_bounds__(512, 2) void k_gemm(
    const unsigned short* __restrict__ Xb, const unsigned short* __restrict__ Yb,
    const float* __restrict__ cbuf, uint32_t* __restrict__ rowkey)
{
  __shared__ __align__(16) char ldsB[2 * 32768];

  const int brow = blockIdx.x * BM;
  const int tid  = threadIdx.x;
  const int wid  = tid >> 6;
  const int lane = tid & 63;
  const int wr = wid >> 1;          // 0..3 -> rows wr*32
  const int wc = wid & 1;           // 0..1 -> cols wc*32 within BN
  const int c15 = lane & 15;
  const int w4  = lane >> 4;
  const int csw = (c15 & 7) << 4;   // read-side XOR (col&7 == c15&7 here)

  // A fragments -> registers (whole K): 16 x dwordx4 per lane = 64 VGPRs
  short8_t a[2][8];
  {
    const char* aBase = (const char*)Xb + (size_t)(brow + wr * 32 + c15) * 512 + w4 * 16;
    #pragma unroll
    for (int m = 0; m < 2; ++m)
      #pragma unroll
      for (int kf = 0; kf < 8; ++kf)
        a[m][kf] = *(const short8_t*)(aBase + m * 8192 + kf * 64);
  }

  STAGEB(0, 0);
  asm volatile("s_waitcnt vmcnt(0)" ::: "memory");
  __builtin_amdgcn_s_barrier();

  f32x4 vmin[2];
  vmin[0] = (f32x4){3.4e38f, 3.4e38f, 3.4e38f, 3.4e38f};
  vmin[1] = vmin[0];

  #pragma unroll 1
  for (int t = 0; t < NT; ++t) {
    const int buf = t & 1;
    const char* bRd = ldsB + buf * 32768 + (wc * 32 + c15) * 512;

    const float cj0 = cbuf[t * 64 + wc * 32 +  0 + c15];
    const float cj1 = cbuf[t * 64 + wc * 32 + 16 + c15];

    if (t + 1 < NT) STAGEB(t + 1, buf ^ 1);

    const f32x4 z = {0.f, 0.f, 0.f, 0.f};
    f32x4 acc00 = z, acc01 = z, acc10 = z, acc11 = z;
    short8_t fb0[8], fb1[8];
    #pragma unroll
    for (int kf = 0; kf < 2; ++kf) { fb0[kf] = RB(0, kf); fb1[kf] = RB(1, kf); }
    __builtin_amdgcn_s_setprio(1);
    #pragma unroll
    for (int kf = 0; kf < 8; ++kf) {
      if (kf < 6) { fb0[kf + 2] = RB(0, kf + 2); fb1[kf + 2] = RB(1, kf + 2); }
      acc00 = __builtin_amdgcn_mfma_f32_16x16x32_bf16(a[0][kf], fb0[kf], acc00, 0, 0, 0);
      acc10 = __builtin_amdgcn_mfma_f32_16x16x32_bf16(a[1][kf], fb0[kf], acc10, 0, 0, 0);
      acc01 = __builtin_amdgcn_mfma_f32_16x16x32_bf16(a[0][kf], fb1[kf], acc01, 0, 0, 0);
      acc11 = __builtin_amdgcn_mfma_f32_16x16x32_bf16(a[1][kf], fb1[kf], acc11, 0, 0, 0);
    }
    __builtin_amdgcn_s_setprio(0);

    const f32x4 c0 = {cj0, cj0, cj0, cj0};
    const f32x4 c1 = {cj1, cj1, cj1, cj1};
    vmin[0] = vmin4(vmin[0], vmin4(c0 - acc00, c1 - acc01));
    vmin[1] = vmin4(vmin[1], vmin4(c0 - acc10, c1 - acc11));

    asm volatile("s_waitcnt vmcnt(0)" ::: "memory");
    __builtin_amdgcn_s_barrier();
  }

  // epilogue: reduce min across the 16 lanes of each column group, then atomicMin.
  // C/D layout: col = lane&15, row = (lane>>4)*4 + reg
  #pragma unroll
  for (int m = 0; m < 2; ++m) {
    #pragma unroll
    for (int r = 0; r < 4; ++r) {
      float v = vmin[m][r];
      v = fminf(v, __shfl_xor(v, 1));
      v = fminf(v, __shfl_xor(v, 2));
      v = fminf(v, __shfl_xor(v, 4));
      v = fminf(v, __shfl_xor(v, 8));
      vmin[m][r] = v;
    }
    if (c15 < 4) {
      float vsel = vmin[m][0];
      vsel = (c15 == 1) ? vmin[m][1] : vsel;
      vsel = (c15 == 2) ? vmin[m][2] : vsel;
      vsel = (c15 == 3) ? vmin[m][3] : vsel;
      const int row = brow + wr * 32 + m * 16 + w4 * 4 + c15;
      atomicMin((unsigned int*)&rowkey[row], fkey(vsel));
    }
  }
}

// ---- K3: sum over rows of (min + 0.5||x||^2)
__global__ void k_rowred(const float* __restrict__ xhalf, const uint32_t* __restrict__ rowkey,
                         float* __restrict__ sum_accum)
{
  __shared__ float sh[4];
  const int i = blockIdx.x * 256 + threadIdx.x;
  float v = funkey(rowkey[i]) + xhalf[i];
  #pragma unroll
  for (int m = 32; m >= 1; m >>= 1) v += __shfl_xor(v, m);
  const int wid = threadIdx.x >> 6, lane = threadIdx.x & 63;
  if (lane == 0) sh[wid] = v;
  __syncthreads();
  if (threadIdx.x == 0) atomicAdd(sum_accum, sh[0] + sh[1] + sh[2] + sh[3]);
}

// ---- K4: out = sum/N + mean(psi)
__global__ void k_final(const float* __restrict__ psi, const float* __restrict__ sum_accum,
                        float* __restrict__ out)
{
  __shared__ float sh[4];
  float s = 0.f;
  for (int i = threadIdx.x; i < MCOLS; i += 256) s += psi[i];
  #pragma unroll
  for (int m = 32; m >= 1; m >>= 1) s += __shfl_xor(s, m);
  const int wid = threadIdx.x >> 6, lane = threadIdx.x & 63;
  if (lane == 0) sh[wid] = s;
  __syncthreads();
  if (threadIdx.x == 0)
    out[0] = sum_accum[0] / (float)NROWS + (sh[0] + sh[1] + sh[2] + sh[3]) / (float)MCOLS;
}

extern "C" void kernel_launch(void* const* d_in, const int* in_sizes, int n_in,
                              void* d_out, int out_size, void* d_ws, size_t ws_size,
                              hipStream_t stream)
{
  const float* X   = (const float*)d_in[0];
  const float* Y   = (const float*)d_in[1];
  const float* psi = (const float*)d_in[2];
  float* out = (float*)d_out;

  char* ws = (char*)d_ws;
  unsigned short* Xb = (unsigned short*)(ws);                                   // 16,777,216 B
  unsigned short* Yb = (unsigned short*)(ws + (size_t)NROWS * DDIM * 2);        //  4,194,304 B
  float* cbuf        = (float*)(ws + (size_t)(NROWS + MCOLS) * DDIM * 2);       //     32,768 B
  uint32_t* rowkey   = (uint32_t*)((char*)cbuf + (size_t)MCOLS * 4);            //    131,072 B
  float* xhalf       = (float*)((char*)rowkey + (size_t)NROWS * 4);             //    131,072 B
  float* sum_accum   = (float*)((char*)xhalf + (size_t)NROWS * 4);              //          4 B

  k_prep  <<<2048, 256, 0, stream>>>(X, Y, psi, Xb, Yb, xhalf, cbuf, rowkey, sum_accum);
  k_gemm  <<<NWG, 512, 0, stream>>>(Xb, Yb, cbuf, rowkey);
  k_rowred<<<NROWS / 256, 256, 0, stream>>>(xhalf, rowkey, sum_accum);
  k_final <<<1, 256, 0, stream>>>(psi, sum_accum, out);
}

// Round 5
// 154.889 us; speedup vs baseline: 1.6852x; 1.1512x over previous
//
#include <hip/hip_runtime.h>
#include <hip/hip_bf16.h>
#include <stdint.h>

#define NROWS 32768
#define MCOLS 8192
#define DDIM  256

#define BM 128            // rows per (persistent) workgroup
#define BN 128            // cols per iteration
#define NT (MCOLS/BN)     // 64 iterations
#define NWG (NROWS/BM)    // 256 workgroups = 1 per CU

typedef __attribute__((ext_vector_type(8))) short short8_t;
typedef __attribute__((ext_vector_type(4))) float f32x4;

__device__ __forceinline__ unsigned short f2bf(float f) {
  uint32_t u = __float_as_uint(f);
  u += 0x7FFFu + ((u >> 16) & 1u);   // round-to-nearest-even
  return (unsigned short)(u >> 16);
}
// order-preserving float -> uint key (integer atomicMin == float min)
__device__ __forceinline__ uint32_t fkey(float f) {
  uint32_t b = __float_as_uint(f);
  return (b & 0x80000000u) ? ~b : (b | 0x80000000u);
}
__device__ __forceinline__ float funkey(uint32_t k) {
  uint32_t b = (k & 0x80000000u) ? (k ^ 0x80000000u) : ~k;
  return __uint_as_float(b);
}
__device__ __forceinline__ f32x4 vmin4(f32x4 x, f32x4 y) {
  f32x4 r;
  r[0] = fminf(x[0], y[0]); r[1] = fminf(x[1], y[1]);
  r[2] = fminf(x[2], y[2]); r[3] = fminf(x[3], y[3]);
  return r;
}

// ---- K1: fused prep: bf16 convert X,Y; xhalf = 0.5||x||^2; cbuf = 0.5||y||^2 - psi;
//          init rowkey; zero accumulator.
__global__ void k_prep(const float* __restrict__ X, const float* __restrict__ Y,
                       const float* __restrict__ psi,
                       unsigned short* __restrict__ Xb, unsigned short* __restrict__ Yb,
                       float* __restrict__ xhalf, float* __restrict__ cbuf,
                       uint32_t* __restrict__ rowkey, float* __restrict__ sum_accum)
{
  const int lane = threadIdx.x & 63;
  const int gw = (blockIdx.x * blockDim.x + threadIdx.x) >> 6;
  const int nw = (gridDim.x * blockDim.x) >> 6;
  for (int row = gw; row < NROWS + MCOLS; row += nw) {
    const bool isX = row < NROWS;
    const int r = isX ? row : row - NROWS;
    const float* src = isX ? (X + (size_t)row * DDIM) : (Y + (size_t)r * DDIM);
    float4 v = ((const float4*)src)[lane];
    ushort4 o;
    o.x = f2bf(v.x); o.y = f2bf(v.y); o.z = f2bf(v.z); o.w = f2bf(v.w);
    if (isX) ((ushort4*)(Xb + (size_t)row * DDIM))[lane] = o;
    else     ((ushort4*)(Yb + (size_t)r   * DDIM))[lane] = o;
    float s = v.x*v.x + v.y*v.y + v.z*v.z + v.w*v.w;
    #pragma unroll
    for (int m = 32; m >= 1; m >>= 1) s += __shfl_xor(s, m);
    if (lane == 0) {
      if (isX) { xhalf[row] = 0.5f * s; rowkey[row] = 0xFFFFFFFFu; }
      else     { cbuf[r] = 0.5f * s - psi[r]; }
    }
  }
  if (blockIdx.x == 0 && threadIdx.x == 0) sum_accum[0] = 0.0f;
}

// stage B tile (128 rows x 512 B = 64 KB) for column-block t_ into ldsB half nb_.
// XOR-swizzled SOURCE + linear global_load_lds dest; read side applies the same
// involution (rule #21): LDS[r][c16] holds global [r][c16 ^ (r&7)].
#define STAGEB(t_, nb_) do {                                                    \
    _Pragma("unroll") for (int _g = 0; _g < 8; ++_g) {                          \
      const int _row = _g * 16 + wid * 2 + (lane >> 5);                         \
      const char* _src = (const char*)Yb + (size_t)((t_) * BN + _row) * 512     \
                         + (((lane & 31) << 4) ^ ((_row & 7) << 4));            \
      __builtin_amdgcn_global_load_lds(                                         \
          (const __attribute__((address_space(1))) uint32_t*)_src,              \
          (__attribute__((address_space(3))) uint32_t*)                         \
              (ldsB + (nb_) * 65536 + (_g * 16 + wid * 2) * 512), 16, 0, 0);    \
    }                                                                           \
  } while (0)

// read one swizzled B fragment: column group n_ (0/1), k-fragment kf_ (0..7)
#define RB(n_, kf_) (*(const short8_t*)(bRd + (n_) * 8192 +                     \
                      ((w4 * 16 + (kf_) * 64) ^ csw)))

// ---- K2: persistent-row MFMA sweep; A (64 rows x K=256 per wave) in registers;
//          B streamed through double-buffered swizzled LDS; 1 barrier/iter.
__global__ __attribute__((amdgpu_flat_work_group_size(512, 512),
                          amdgpu_waves_per_eu(2, 2)))
void k_gemm(const unsigned short* __restrict__ Xb, const unsigned short* __restrict__ Yb,
            const float* __restrict__ cbuf, uint32_t* __restrict__ rowkey)
{
  __shared__ __align__(16) char ldsB[2 * 65536];   // 128 KiB double-buffered B

  const int brow = blockIdx.x * BM;
  const int tid  = threadIdx.x;
  const int wid  = tid >> 6;
  const int lane = tid & 63;
  const int wr = wid >> 2;          // 0..1 -> rows wr*64
  const int wc = wid & 3;           // 0..3 -> cols wc*32 within BN
  const int c15 = lane & 15;
  const int w4  = lane >> 4;
  const int csw = (c15 & 7) << 4;   // read-side XOR (B-row & 7 == c15 & 7)

  // A fragments -> registers (64 rows x whole K): 32 x dwordx4 per lane = 128 VGPRs
  short8_t a[4][8];
  {
    const char* aBase = (const char*)Xb + (size_t)(brow + wr * 64 + c15) * 512 + w4 * 16;
    #pragma unroll
    for (int m = 0; m < 4; ++m)
      #pragma unroll
      for (int kf = 0; kf < 8; ++kf)
        a[m][kf] = *(const short8_t*)(aBase + m * 16 * 512 + kf * 64);
  }

  STAGEB(0, 0);
  asm volatile("s_waitcnt vmcnt(0)" ::: "memory");
  __builtin_amdgcn_s_barrier();

  f32x4 vmin[4];
  #pragma unroll
  for (int m = 0; m < 4; ++m)
    vmin[m] = (f32x4){3.4e38f, 3.4e38f, 3.4e38f, 3.4e38f};

  #pragma unroll 1
  for (int t = 0; t < NT; ++t) {
    const int buf = t & 1;
    const char* bRd = ldsB + buf * 65536 + (wc * 32 + c15) * 512;

    const float cj0 = cbuf[t * BN + wc * 32 +  0 + c15];
    const float cj1 = cbuf[t * BN + wc * 32 + 16 + c15];

    if (t + 1 < NT) STAGEB(t + 1, buf ^ 1);

    const f32x4 z = {0.f, 0.f, 0.f, 0.f};
    f32x4 acc[4][2];
    #pragma unroll
    for (int m = 0; m < 4; ++m) { acc[m][0] = z; acc[m][1] = z; }

    short8_t fb0[8], fb1[8];
    #pragma unroll
    for (int kf = 0; kf < 2; ++kf) { fb0[kf] = RB(0, kf); fb1[kf] = RB(1, kf); }
    __builtin_amdgcn_s_setprio(1);
    #pragma unroll
    for (int kf = 0; kf < 8; ++kf) {
      if (kf < 6) { fb0[kf + 2] = RB(0, kf + 2); fb1[kf + 2] = RB(1, kf + 2); }
      #pragma unroll
      for (int m = 0; m < 4; ++m)
        acc[m][0] = __builtin_amdgcn_mfma_f32_16x16x32_bf16(a[m][kf], fb0[kf], acc[m][0], 0, 0, 0);
      #pragma unroll
      for (int m = 0; m < 4; ++m)
        acc[m][1] = __builtin_amdgcn_mfma_f32_16x16x32_bf16(a[m][kf], fb1[kf], acc[m][1], 0, 0, 0);
    }
    __builtin_amdgcn_s_setprio(0);

    const f32x4 c0 = {cj0, cj0, cj0, cj0};
    const f32x4 c1 = {cj1, cj1, cj1, cj1};
    #pragma unroll
    for (int m = 0; m < 4; ++m)
      vmin[m] = vmin4(vmin[m], vmin4(c0 - acc[m][0], c1 - acc[m][1]));

    asm volatile("s_waitcnt vmcnt(0)" ::: "memory");
    __builtin_amdgcn_s_barrier();
  }

  // epilogue: reduce min across the 16 lanes of each column group, then atomicMin.
  // C/D layout: col = lane&15, row = (lane>>4)*4 + reg
  #pragma unroll
  for (int m = 0; m < 4; ++m) {
    #pragma unroll
    for (int r = 0; r < 4; ++r) {
      float v = vmin[m][r];
      v = fminf(v, __shfl_xor(v, 1));
      v = fminf(v, __shfl_xor(v, 2));
      v = fminf(v, __shfl_xor(v, 4));
      v = fminf(v, __shfl_xor(v, 8));
      vmin[m][r] = v;
    }
    if (c15 < 4) {
      float vsel = vmin[m][0];
      vsel = (c15 == 1) ? vmin[m][1] : vsel;
      vsel = (c15 == 2) ? vmin[m][2] : vsel;
      vsel = (c15 == 3) ? vmin[m][3] : vsel;
      const int row = brow + wr * 64 + m * 16 + w4 * 4 + c15;
      atomicMin((unsigned int*)&rowkey[row], fkey(vsel));
    }
  }
}

// ---- K3: sum over rows of (min + 0.5||x||^2)
__global__ void k_rowred(const float* __restrict__ xhalf, const uint32_t* __restrict__ rowkey,
                         float* __restrict__ sum_accum)
{
  __shared__ float sh[4];
  const int i = blockIdx.x * 256 + threadIdx.x;
  float v = funkey(rowkey[i]) + xhalf[i];
  #pragma unroll
  for (int m = 32; m >= 1; m >>= 1) v += __shfl_xor(v, m);
  const int wid = threadIdx.x >> 6, lane = threadIdx.x & 63;
  if (lane == 0) sh[wid] = v;
  __syncthreads();
  if (threadIdx.x == 0) atomicAdd(sum_accum, sh[0] + sh[1] + sh[2] + sh[3]);
}

// ---- K4: out = sum/N + mean(psi)
__global__ void k_final(const float* __restrict__ psi, const float* __restrict__ sum_accum,
                        float* __restrict__ out)
{
  __shared__ float sh[4];
  float s = 0.f;
  for (int i = threadIdx.x; i < MCOLS; i += 256) s += psi[i];
  #pragma unroll
  for (int m = 32; m >= 1; m >>= 1) s += __shfl_xor(s, m);
  const int wid = threadIdx.x >> 6, lane = threadIdx.x & 63;
  if (lane == 0) sh[wid] = s;
  __syncthreads();
  if (threadIdx.x == 0)
    out[0] = sum_accum[0] / (float)NROWS + (sh[0] + sh[1] + sh[2] + sh[3]) / (float)MCOLS;
}

extern "C" void kernel_launch(void* const* d_in, const int* in_sizes, int n_in,
                              void* d_out, int out_size, void* d_ws, size_t ws_size,
                              hipStream_t stream)
{
  const float* X   = (const float*)d_in[0];
  const float* Y   = (const float*)d_in[1];
  const float* psi = (const float*)d_in[2];
  float* out = (float*)d_out;

  char* ws = (char*)d_ws;
  unsigned short* Xb = (unsigned short*)(ws);                                   // 16,777,216 B
  unsigned short* Yb = (unsigned short*)(ws + (size_t)NROWS * DDIM * 2);        //  4,194,304 B
  float* cbuf        = (float*)(ws + (size_t)(NROWS + MCOLS) * DDIM * 2);       //     32,768 B
  uint32_t* rowkey   = (uint32_t*)((char*)cbuf + (size_t)MCOLS * 4);            //    131,072 B
  float* xhalf       = (float*)((char*)rowkey + (size_t)NROWS * 4);             //    131,072 B
  float* sum_accum   = (float*)((char*)xhalf + (size_t)NROWS * 4);              //          4 B

  k_prep  <<<2048, 256, 0, stream>>>(X, Y, psi, Xb, Yb, xhalf, cbuf, rowkey, sum_accum);
  k_gemm  <<<NWG, 512, 0, stream>>>(Xb, Yb, cbuf, rowkey);
  k_rowred<<<NROWS / 256, 256, 0, stream>>>(xhalf, rowkey, sum_accum);
  k_final <<<1, 256, 0, stream>>>(psi, sum_accum, out);
}

// Round 6
// 153.999 us; speedup vs baseline: 1.6950x; 1.0058x over previous
//
#include <hip/hip_runtime.h>
#include <hip/hip_bf16.h>
#include <stdint.h>

#define NROWS 32768
#define MCOLS 8192
#define DDIM  256

#define BM 128            // rows per (persistent) workgroup
#define BN 128            // cols per iteration
#define NT (MCOLS/BN)     // 64 iterations
#define NWG (NROWS/BM)    // 256 workgroups = 1 per CU

typedef __attribute__((ext_vector_type(8))) short short8_t;
typedef __attribute__((ext_vector_type(4))) float f32x4;

__device__ __forceinline__ unsigned short f2bf(float f) {
  uint32_t u = __float_as_uint(f);
  u += 0x7FFFu + ((u >> 16) & 1u);   // round-to-nearest-even
  return (unsigned short)(u >> 16);
}
// order-preserving float -> uint key (integer atomicMin == float min)
__device__ __forceinline__ uint32_t fkey(float f) {
  uint32_t b = __float_as_uint(f);
  return (b & 0x80000000u) ? ~b : (b | 0x80000000u);
}
__device__ __forceinline__ float funkey(uint32_t k) {
  uint32_t b = (k & 0x80000000u) ? (k ^ 0x80000000u) : ~k;
  return __uint_as_float(b);
}
__device__ __forceinline__ f32x4 vmin4(f32x4 x, f32x4 y) {
  f32x4 r;
  r[0] = fminf(x[0], y[0]); r[1] = fminf(x[1], y[1]);
  r[2] = fminf(x[2], y[2]); r[3] = fminf(x[3], y[3]);
  return r;
}

// ---- K1: fused prep: bf16 convert X,Y; xhalf = 0.5||x||^2; cbuf = 0.5||y||^2 - psi;
//          init rowkey; zero accumulator.
__global__ void k_prep(const float* __restrict__ X, const float* __restrict__ Y,
                       const float* __restrict__ psi,
                       unsigned short* __restrict__ Xb, unsigned short* __restrict__ Yb,
                       float* __restrict__ xhalf, float* __restrict__ cbuf,
                       uint32_t* __restrict__ rowkey, float* __restrict__ sum_accum)
{
  const int lane = threadIdx.x & 63;
  const int gw = (blockIdx.x * blockDim.x + threadIdx.x) >> 6;
  const int nw = (gridDim.x * blockDim.x) >> 6;
  for (int row = gw; row < NROWS + MCOLS; row += nw) {
    const bool isX = row < NROWS;
    const int r = isX ? row : row - NROWS;
    const float* src = isX ? (X + (size_t)row * DDIM) : (Y + (size_t)r * DDIM);
    float4 v = ((const float4*)src)[lane];
    ushort4 o;
    o.x = f2bf(v.x); o.y = f2bf(v.y); o.z = f2bf(v.z); o.w = f2bf(v.w);
    if (isX) ((ushort4*)(Xb + (size_t)row * DDIM))[lane] = o;
    else     ((ushort4*)(Yb + (size_t)r   * DDIM))[lane] = o;
    float s = v.x*v.x + v.y*v.y + v.z*v.z + v.w*v.w;
    #pragma unroll
    for (int m = 32; m >= 1; m >>= 1) s += __shfl_xor(s, m);
    if (lane == 0) {
      if (isX) { xhalf[row] = 0.5f * s; rowkey[row] = 0xFFFFFFFFu; }
      else     { cbuf[r] = 0.5f * s - psi[r]; }
    }
  }
  if (blockIdx.x == 0 && threadIdx.x == 0) sum_accum[0] = 0.0f;
}

// stage B tile (128 rows x 512 B = 64 KB) for column-block t_ into ldsB half nb_.
// FULL 4-bit XOR swizzle: LDS[r][c16] = global[r][c16 ^ (r&15)] (16B chunks).
// Source column is pre-permuted (still within one 512B row -> coalesced);
// global_load_lds dest stays linear (rule #21).
#define STAGEB(t_, nb_) do {                                                    \
    _Pragma("unroll") for (int _g = 0; _g < 8; ++_g) {                          \
      const int _row = _g * 16 + wid * 2 + (lane >> 5);                         \
      const char* _src = (const char*)Yb + (size_t)((t_) * BN + _row) * 512     \
                         + ((((lane & 31) ^ (_row & 15)) << 4));                \
      __builtin_amdgcn_global_load_lds(                                         \
          (const __attribute__((address_space(1))) uint32_t*)_src,              \
          (__attribute__((address_space(3))) uint32_t*)                         \
              (ldsB + (nb_) * 65536 + (_g * 16 + wid * 2) * 512), 16, 0, 0);    \
    }                                                                           \
  } while (0)

// read one swizzled B fragment: column group n_ (0/1), k-fragment kf_ (0..7)
#define RB(n_, kf_) (*(const short8_t*)(bRd + (n_) * 8192 +                     \
                      ((w4 * 16 + (kf_) * 64) ^ csw)))

// ---- K2: persistent-row MFMA sweep; A (64 rows x K=256 per wave) in registers;
//          B streamed through double-buffered swizzled LDS; 1 barrier/iter.
__global__ __attribute__((amdgpu_flat_work_group_size(512, 512),
                          amdgpu_waves_per_eu(2, 2)))
void k_gemm(const unsigned short* __restrict__ Xb, const unsigned short* __restrict__ Yb,
            const float* __restrict__ cbuf, uint32_t* __restrict__ rowkey)
{
  __shared__ __align__(16) char ldsB[2 * 65536];   // 128 KiB double-buffered B

  const int brow = blockIdx.x * BM;
  const int tid  = threadIdx.x;
  const int wid  = tid >> 6;
  const int lane = tid & 63;
  const int wr = wid >> 2;          // 0..1 -> rows wr*64
  const int wc = wid & 3;           // 0..3 -> cols wc*32 within BN
  const int c15 = lane & 15;
  const int w4  = lane >> 4;
  const int csw = c15 << 4;         // read-side XOR: LDS-row & 15 == c15

  // A fragments -> registers (64 rows x whole K): 32 x dwordx4 per lane = 128 VGPRs
  short8_t a[4][8];
  {
    const char* aBase = (const char*)Xb + (size_t)(brow + wr * 64 + c15) * 512 + w4 * 16;
    #pragma unroll
    for (int m = 0; m < 4; ++m)
      #pragma unroll
      for (int kf = 0; kf < 8; ++kf)
        a[m][kf] = *(const short8_t*)(aBase + m * 16 * 512 + kf * 64);
  }

  STAGEB(0, 0);
  asm volatile("s_waitcnt vmcnt(0)" ::: "memory");
  __builtin_amdgcn_s_barrier();

  f32x4 vmin[4];
  #pragma unroll
  for (int m = 0; m < 4; ++m)
    vmin[m] = (f32x4){3.4e38f, 3.4e38f, 3.4e38f, 3.4e38f};

  #pragma unroll 1
  for (int t = 0; t < NT; ++t) {
    const int buf = t & 1;
    const char* bRd = ldsB + buf * 65536 + (wc * 32 + c15) * 512;

    const float cj0 = cbuf[t * BN + wc * 32 +  0 + c15];
    const float cj1 = cbuf[t * BN + wc * 32 + 16 + c15];

    if (t + 1 < NT) STAGEB(t + 1, buf ^ 1);

    const f32x4 z = {0.f, 0.f, 0.f, 0.f};
    f32x4 acc[4][2];
    #pragma unroll
    for (int m = 0; m < 4; ++m) { acc[m][0] = z; acc[m][1] = z; }

    short8_t fb0[8], fb1[8];
    #pragma unroll
    for (int kf = 0; kf < 2; ++kf) { fb0[kf] = RB(0, kf); fb1[kf] = RB(1, kf); }
    __builtin_amdgcn_s_setprio(1);
    #pragma unroll
    for (int kf = 0; kf < 8; ++kf) {
      if (kf < 6) { fb0[kf + 2] = RB(0, kf + 2); fb1[kf + 2] = RB(1, kf + 2); }
      #pragma unroll
      for (int m = 0; m < 4; ++m)
        acc[m][0] = __builtin_amdgcn_mfma_f32_16x16x32_bf16(a[m][kf], fb0[kf], acc[m][0], 0, 0, 0);
      #pragma unroll
      for (int m = 0; m < 4; ++m)
        acc[m][1] = __builtin_amdgcn_mfma_f32_16x16x32_bf16(a[m][kf], fb1[kf], acc[m][1], 0, 0, 0);
    }
    __builtin_amdgcn_s_setprio(0);

    const f32x4 c0 = {cj0, cj0, cj0, cj0};
    const f32x4 c1 = {cj1, cj1, cj1, cj1};
    #pragma unroll
    for (int m = 0; m < 4; ++m)
      vmin[m] = vmin4(vmin[m], vmin4(c0 - acc[m][0], c1 - acc[m][1]));

    asm volatile("s_waitcnt vmcnt(0)" ::: "memory");
    __builtin_amdgcn_s_barrier();
  }

  // epilogue: reduce min across the 16 lanes of each column group, then atomicMin.
  // C/D layout: col = lane&15, row = (lane>>4)*4 + reg
  #pragma unroll
  for (int m = 0; m < 4; ++m) {
    #pragma unroll
    for (int r = 0; r < 4; ++r) {
      float v = vmin[m][r];
      v = fminf(v, __shfl_xor(v, 1));
      v = fminf(v, __shfl_xor(v, 2));
      v = fminf(v, __shfl_xor(v, 4));
      v = fminf(v, __shfl_xor(v, 8));
      vmin[m][r] = v;
    }
    if (c15 < 4) {
      float vsel = vmin[m][0];
      vsel = (c15 == 1) ? vmin[m][1] : vsel;
      vsel = (c15 == 2) ? vmin[m][2] : vsel;
      vsel = (c15 == 3) ? vmin[m][3] : vsel;
      const int row = brow + wr * 64 + m * 16 + w4 * 4 + c15;
      atomicMin((unsigned int*)&rowkey[row], fkey(vsel));
    }
  }
}

// ---- K3: sum over rows of (min + 0.5||x||^2)
__global__ void k_rowred(const float* __restrict__ xhalf, const uint32_t* __restrict__ rowkey,
                         float* __restrict__ sum_accum)
{
  __shared__ float sh[4];
  const int i = blockIdx.x * 256 + threadIdx.x;
  float v = funkey(rowkey[i]) + xhalf[i];
  #pragma unroll
  for (int m = 32; m >= 1; m >>= 1) v += __shfl_xor(v, m);
  const int wid = threadIdx.x >> 6, lane = threadIdx.x & 63;
  if (lane == 0) sh[wid] = v;
  __syncthreads();
  if (threadIdx.x == 0) atomicAdd(sum_accum, sh[0] + sh[1] + sh[2] + sh[3]);
}

// ---- K4: out = sum/N + mean(psi)
__global__ void k_final(const float* __restrict__ psi, const float* __restrict__ sum_accum,
                        float* __restrict__ out)
{
  __shared__ float sh[4];
  float s = 0.f;
  for (int i = threadIdx.x; i < MCOLS; i += 256) s += psi[i];
  #pragma unroll
  for (int m = 32; m >= 1; m >>= 1) s += __shfl_xor(s, m);
  const int wid = threadIdx.x >> 6, lane = threadIdx.x & 63;
  if (lane == 0) sh[wid] = s;
  __syncthreads();
  if (threadIdx.x == 0)
    out[0] = sum_accum[0] / (float)NROWS + (sh[0] + sh[1] + sh[2] + sh[3]) / (float)MCOLS;
}

extern "C" void kernel_launch(void* const* d_in, const int* in_sizes, int n_in,
                              void* d_out, int out_size, void* d_ws, size_t ws_size,
                              hipStream_t stream)
{
  const float* X   = (const float*)d_in[0];
  const float* Y   = (const float*)d_in[1];
  const float* psi = (const float*)d_in[2];
  float* out = (float*)d_out;

  char* ws = (char*)d_ws;
  unsigned short* Xb = (unsigned short*)(ws);                                   // 16,777,216 B
  unsigned short* Yb = (unsigned short*)(ws + (size_t)NROWS * DDIM * 2);        //  4,194,304 B
  float* cbuf        = (float*)(ws + (size_t)(NROWS + MCOLS) * DDIM * 2);       //     32,768 B
  uint32_t* rowkey   = (uint32_t*)((char*)cbuf + (size_t)MCOLS * 4);            //    131,072 B
  float* xhalf       = (float*)((char*)rowkey + (size_t)NROWS * 4);             //    131,072 B
  float* sum_accum   = (float*)((char*)xhalf + (size_t)NROWS * 4);              //          4 B

  k_prep  <<<2048, 256, 0, stream>>>(X, Y, psi, Xb, Yb, xhalf, cbuf, rowkey, sum_accum);
  k_gemm  <<<NWG, 512, 0, stream>>>(Xb, Yb, cbuf, rowkey);
  k_rowred<<<NROWS / 256, 256, 0, stream>>>(xhalf, rowkey, sum_accum);
  k_final <<<1, 256, 0, stream>>>(psi, sum_accum, out);
}

// Round 7
// 97.306 us; speedup vs baseline: 2.6825x; 1.5826x over previous
//
#include <hip/hip_runtime.h>
#include <hip/hip_bf16.h>
#include <stdint.h>

#define NROWS 32768
#define MCOLS 8192
#define DDIM  256

#define BM 128            // rows per (persistent) workgroup
#define BN 128            // cols per iteration
#define NT (MCOLS/BN)     // 64 iterations
#define NWG (NROWS/BM)    // 256 workgroups = 1 per CU

typedef __attribute__((ext_vector_type(8))) int   int8v;
typedef __attribute__((ext_vector_type(4))) int   int4v;
typedef __attribute__((ext_vector_type(4))) float f32x4;

// pack 4 f32 -> 4 fp8 e4m3 (OCP on gfx950) via HW converter (RNE, saturating)
__device__ __forceinline__ uint32_t pk4_fp8(float4 v) {
  int p = __builtin_amdgcn_cvt_pk_fp8_f32(v.x, v.y, 0, false);   // bytes 0,1
  p = __builtin_amdgcn_cvt_pk_fp8_f32(v.z, v.w, p, true);        // bytes 2,3
  return (uint32_t)p;
}
// order-preserving float -> uint key (integer atomicMin == float min)
__device__ __forceinline__ uint32_t fkey(float f) {
  uint32_t b = __float_as_uint(f);
  return (b & 0x80000000u) ? ~b : (b | 0x80000000u);
}
__device__ __forceinline__ float funkey(uint32_t k) {
  uint32_t b = (k & 0x80000000u) ? (k ^ 0x80000000u) : ~k;
  return __uint_as_float(b);
}
__device__ __forceinline__ f32x4 vmin4(f32x4 x, f32x4 y) {
  f32x4 r;
  r[0] = fminf(x[0], y[0]); r[1] = fminf(x[1], y[1]);
  r[2] = fminf(x[2], y[2]); r[3] = fminf(x[3], y[3]);
  return r;
}

// ---- K1: fused prep: fp8 convert X,Y; xhalf = 0.5||x||^2 (exact fp32);
//          cbuf = 0.5||y||^2 - psi (exact); init rowkey; zero accumulator.
__global__ void k_prep(const float* __restrict__ X, const float* __restrict__ Y,
                       const float* __restrict__ psi,
                       uint32_t* __restrict__ Xq, uint32_t* __restrict__ Yq,
                       float* __restrict__ xhalf, float* __restrict__ cbuf,
                       uint32_t* __restrict__ rowkey, float* __restrict__ sum_accum)
{
  const int lane = threadIdx.x & 63;
  const int gw = (blockIdx.x * blockDim.x + threadIdx.x) >> 6;
  const int nw = (gridDim.x * blockDim.x) >> 6;
  for (int row = gw; row < NROWS + MCOLS; row += nw) {
    const bool isX = row < NROWS;
    const int r = isX ? row : row - NROWS;
    const float* src = isX ? (X + (size_t)row * DDIM) : (Y + (size_t)r * DDIM);
    float4 v = ((const float4*)src)[lane];          // 4 elems per lane, 256 per row
    const uint32_t pk = pk4_fp8(v);
    if (isX) Xq[(size_t)row * 64 + lane] = pk;
    else     Yq[(size_t)r   * 64 + lane] = pk;
    float s = v.x*v.x + v.y*v.y + v.z*v.z + v.w*v.w;
    #pragma unroll
    for (int m = 32; m >= 1; m >>= 1) s += __shfl_xor(s, m);
    if (lane == 0) {
      if (isX) { xhalf[row] = 0.5f * s; rowkey[row] = 0xFFFFFFFFu; }
      else     { cbuf[r] = 0.5f * s - psi[r]; }
    }
  }
  if (blockIdx.x == 0 && threadIdx.x == 0) sum_accum[0] = 0.0f;
}

// stage fp8 B tile (128 col-rows x 256 B = 32 KB) for column-block t_ into half nb_.
// 4-bit XOR involution at 16B granularity: LDS[r][c16] = global[r][c16 ^ (r&15)].
// Source permuted within each 256B row (coalesced); LDS dest linear (rule #21).
#define STAGEB(t_, nb_) do {                                                    \
    _Pragma("unroll") for (int _g = 0; _g < 4; ++_g) {                          \
      const int _row = _g * 32 + wid * 4 + (lane >> 4);                         \
      const char* _src = (const char*)Yq + (size_t)((t_) * BN + _row) * 256     \
                         + ((((lane & 15) ^ (_row & 15)) << 4));                \
      __builtin_amdgcn_global_load_lds(                                         \
          (const __attribute__((address_space(1))) uint32_t*)_src,              \
          (__attribute__((address_space(3))) uint32_t*)                         \
              (ldsB + (nb_) * 32768 + (_g * 32 + wid * 4) * 256), 16, 0, 0);    \
    }                                                                           \
  } while (0)

// read one swizzled 16B chunk of B: col group n_ (0/1), K-chunk kc_ (0/1), half h_ (0/1)
#define RB16(n_, kc_, h_)                                                       \
  (*(const int4v*)(bRd + ((wc * 32 + (n_) * 16 + c15) << 8) +                   \
                   ((((kc_) * 8 + w4 * 2 + (h_)) ^ c15) << 4)))

// ---- K2: persistent-row MX-fp8 MFMA sweep; A (64 rows x K=256) in registers;
//          B streamed through double-buffered swizzled LDS; 1 barrier/iter.
__global__ __attribute__((amdgpu_flat_work_group_size(512, 512),
                          amdgpu_waves_per_eu(2, 2)))
void k_gemm(const uint32_t* __restrict__ Xq, const uint32_t* __restrict__ Yq,
            const float* __restrict__ cbuf, uint32_t* __restrict__ rowkey)
{
  __shared__ __align__(16) char ldsB[2 * 32768];   // 64 KiB double-buffered B (fp8)

  const int brow = blockIdx.x * BM;
  const int tid  = threadIdx.x;
  const int wid  = tid >> 6;
  const int lane = tid & 63;
  const int wr = wid >> 2;          // 0..1 -> rows wr*64
  const int wc = wid & 3;           // 0..3 -> cols wc*32 within BN
  const int c15 = lane & 15;
  const int w4  = lane >> 4;

  // A fragments -> registers: lane holds rows (wr*64 + m*16 + c15), K-chunk w4*32B,
  // for m 0..3, kc 0..1 -> 8 x 32B = 64 VGPRs total.
  int8v a[4][2];
  {
    const char* aBase = (const char*)Xq + ((size_t)(brow + wr * 64 + c15) << 8) + w4 * 32;
    #pragma unroll
    for (int m = 0; m < 4; ++m)
      #pragma unroll
      for (int kc = 0; kc < 2; ++kc)
        a[m][kc] = *(const int8v*)(aBase + m * 16 * 256 + kc * 128);
  }

  STAGEB(0, 0);
  asm volatile("s_waitcnt vmcnt(0)" ::: "memory");
  __builtin_amdgcn_s_barrier();

  f32x4 vmin[4];
  #pragma unroll
  for (int m = 0; m < 4; ++m)
    vmin[m] = (f32x4){3.4e38f, 3.4e38f, 3.4e38f, 3.4e38f};

  #pragma unroll 1
  for (int t = 0; t < NT; ++t) {
    const int buf = t & 1;
    const char* bRd = ldsB + buf * 32768;

    const float cj0 = cbuf[t * BN + wc * 32 +  0 + c15];
    const float cj1 = cbuf[t * BN + wc * 32 + 16 + c15];

    if (t + 1 < NT) STAGEB(t + 1, buf ^ 1);

    // load all B fragments for this tile: 8 x ds_read_b128
    int8v bf[2][2];
    #pragma unroll
    for (int n = 0; n < 2; ++n)
      #pragma unroll
      for (int kc = 0; kc < 2; ++kc) {
        const int4v lo = RB16(n, kc, 0);
        const int4v hi = RB16(n, kc, 1);
        bf[n][kc] = (int8v){lo[0], lo[1], lo[2], lo[3], hi[0], hi[1], hi[2], hi[3]};
      }

    const f32x4 z = {0.f, 0.f, 0.f, 0.f};
    f32x4 acc[4][2];
    #pragma unroll
    for (int m = 0; m < 4; ++m) { acc[m][0] = z; acc[m][1] = z; }

    __builtin_amdgcn_s_setprio(1);
    #pragma unroll
    for (int kc = 0; kc < 2; ++kc) {
      #pragma unroll
      for (int m = 0; m < 4; ++m)
        acc[m][0] = __builtin_amdgcn_mfma_scale_f32_16x16x128_f8f6f4(
            a[m][kc], bf[0][kc], acc[m][0], 0, 0, 0, 0x7F, 0, 0x7F);
      #pragma unroll
      for (int m = 0; m < 4; ++m)
        acc[m][1] = __builtin_amdgcn_mfma_scale_f32_16x16x128_f8f6f4(
            a[m][kc], bf[1][kc], acc[m][1], 0, 0, 0, 0x7F, 0, 0x7F);
    }
    __builtin_amdgcn_s_setprio(0);

    const f32x4 c0 = {cj0, cj0, cj0, cj0};
    const f32x4 c1 = {cj1, cj1, cj1, cj1};
    #pragma unroll
    for (int m = 0; m < 4; ++m)
      vmin[m] = vmin4(vmin[m], vmin4(c0 - acc[m][0], c1 - acc[m][1]));

    asm volatile("s_waitcnt vmcnt(0)" ::: "memory");
    __builtin_amdgcn_s_barrier();
  }

  // epilogue: reduce min across the 16 lanes of each column group, then atomicMin.
  // C/D layout (shape-determined): col = lane&15, row = (lane>>4)*4 + reg
  #pragma unroll
  for (int m = 0; m < 4; ++m) {
    #pragma unroll
    for (int r = 0; r < 4; ++r) {
      float v = vmin[m][r];
      v = fminf(v, __shfl_xor(v, 1));
      v = fminf(v, __shfl_xor(v, 2));
      v = fminf(v, __shfl_xor(v, 4));
      v = fminf(v, __shfl_xor(v, 8));
      vmin[m][r] = v;
    }
    if (c15 < 4) {
      float vsel = vmin[m][0];
      vsel = (c15 == 1) ? vmin[m][1] : vsel;
      vsel = (c15 == 2) ? vmin[m][2] : vsel;
      vsel = (c15 == 3) ? vmin[m][3] : vsel;
      const int row = brow + wr * 64 + m * 16 + w4 * 4 + c15;
      atomicMin((unsigned int*)&rowkey[row], fkey(vsel));
    }
  }
}

// ---- K3: sum over rows of (min + 0.5||x||^2)
__global__ void k_rowred(const float* __restrict__ xhalf, const uint32_t* __restrict__ rowkey,
                         float* __restrict__ sum_accum)
{
  __shared__ float sh[4];
  const int i = blockIdx.x * 256 + threadIdx.x;
  float v = funkey(rowkey[i]) + xhalf[i];
  #pragma unroll
  for (int m = 32; m >= 1; m >>= 1) v += __shfl_xor(v, m);
  const int wid = threadIdx.x >> 6, lane = threadIdx.x & 63;
  if (lane == 0) sh[wid] = v;
  __syncthreads();
  if (threadIdx.x == 0) atomicAdd(sum_accum, sh[0] + sh[1] + sh[2] + sh[3]);
}

// ---- K4: out = sum/N + mean(psi)
__global__ void k_final(const float* __restrict__ psi, const float* __restrict__ sum_accum,
                        float* __restrict__ out)
{
  __shared__ float sh[4];
  float s = 0.f;
  for (int i = threadIdx.x; i < MCOLS; i += 256) s += psi[i];
  #pragma unroll
  for (int m = 32; m >= 1; m >>= 1) s += __shfl_xor(s, m);
  const int wid = threadIdx.x >> 6, lane = threadIdx.x & 63;
  if (lane == 0) sh[wid] = s;
  __syncthreads();
  if (threadIdx.x == 0)
    out[0] = sum_accum[0] / (float)NROWS + (sh[0] + sh[1] + sh[2] + sh[3]) / (float)MCOLS;
}

extern "C" void kernel_launch(void* const* d_in, const int* in_sizes, int n_in,
                              void* d_out, int out_size, void* d_ws, size_t ws_size,
                              hipStream_t stream)
{
  const float* X   = (const float*)d_in[0];
  const float* Y   = (const float*)d_in[1];
  const float* psi = (const float*)d_in[2];
  float* out = (float*)d_out;

  char* ws = (char*)d_ws;
  uint32_t* Xq     = (uint32_t*)(ws);                                           // 8,388,608 B
  uint32_t* Yq     = (uint32_t*)(ws + (size_t)NROWS * DDIM);                    // 2,097,152 B
  float* cbuf      = (float*)(ws + (size_t)(NROWS + MCOLS) * DDIM);             //    32,768 B
  uint32_t* rowkey = (uint32_t*)((char*)cbuf + (size_t)MCOLS * 4);              //   131,072 B
  float* xhalf     = (float*)((char*)rowkey + (size_t)NROWS * 4);               //   131,072 B
  float* sum_accum = (float*)((char*)xhalf + (size_t)NROWS * 4);                //         4 B

  k_prep  <<<2048, 256, 0, stream>>>(X, Y, psi, Xq, Yq, xhalf, cbuf, rowkey, sum_accum);
  k_gemm  <<<NWG, 512, 0, stream>>>(Xq, Yq, cbuf, rowkey);
  k_rowred<<<NROWS / 256, 256, 0, stream>>>(xhalf, rowkey, sum_accum);
  k_final <<<1, 256, 0, stream>>>(psi, sum_accum, out);
}

// Round 8
// 93.698 us; speedup vs baseline: 2.7858x; 1.0385x over previous
//
#include <hip/hip_runtime.h>
#include <hip/hip_bf16.h>
#include <stdint.h>

#define NROWS 32768
#define MCOLS 8192
#define DDIM  256

#define BM 128            // rows per (persistent) workgroup
#define BN 128            // cols per iteration
#define NT (MCOLS/BN)     // 64 iterations
#define NWG (NROWS/BM)    // 256 workgroups = 1 per CU

typedef __attribute__((ext_vector_type(8))) int   int8v;
typedef __attribute__((ext_vector_type(4))) int   int4v;
typedef __attribute__((ext_vector_type(4))) float f32x4;

// pack 4 f32 -> 4 fp8 e4m3 (OCP on gfx950) via HW converter (RNE, saturating)
__device__ __forceinline__ uint32_t pk4_fp8(float4 v) {
  int p = __builtin_amdgcn_cvt_pk_fp8_f32(v.x, v.y, 0, false);   // bytes 0,1
  p = __builtin_amdgcn_cvt_pk_fp8_f32(v.z, v.w, p, true);        // bytes 2,3
  return (uint32_t)p;
}
// order-preserving float -> uint key (integer atomicMin == float min)
__device__ __forceinline__ uint32_t fkey(float f) {
  uint32_t b = __float_as_uint(f);
  return (b & 0x80000000u) ? ~b : (b | 0x80000000u);
}
__device__ __forceinline__ float funkey(uint32_t k) {
  uint32_t b = (k & 0x80000000u) ? (k ^ 0x80000000u) : ~k;
  return __uint_as_float(b);
}
__device__ __forceinline__ f32x4 vmin4(f32x4 x, f32x4 y) {
  f32x4 r;
  r[0] = fminf(x[0], y[0]); r[1] = fminf(x[1], y[1]);
  r[2] = fminf(x[2], y[2]); r[3] = fminf(x[3], y[3]);
  return r;
}

// ---- K1: fused prep: fp8 convert X,Y; xhalf = 0.5||x||^2 (exact fp32);
//          cbuf = 0.5||y||^2 - psi (exact); init rowkey; zero accumulator.
__global__ void k_prep(const float* __restrict__ X, const float* __restrict__ Y,
                       const float* __restrict__ psi,
                       uint32_t* __restrict__ Xq, uint32_t* __restrict__ Yq,
                       float* __restrict__ xhalf, float* __restrict__ cbuf,
                       uint32_t* __restrict__ rowkey, float* __restrict__ sum_accum)
{
  const int lane = threadIdx.x & 63;
  const int gw = (blockIdx.x * blockDim.x + threadIdx.x) >> 6;
  const int nw = (gridDim.x * blockDim.x) >> 6;
  for (int row = gw; row < NROWS + MCOLS; row += nw) {
    const bool isX = row < NROWS;
    const int r = isX ? row : row - NROWS;
    const float* src = isX ? (X + (size_t)row * DDIM) : (Y + (size_t)r * DDIM);
    float4 v = ((const float4*)src)[lane];          // 4 elems per lane, 256 per row
    const uint32_t pk = pk4_fp8(v);
    if (isX) Xq[(size_t)row * 64 + lane] = pk;
    else     Yq[(size_t)r   * 64 + lane] = pk;
    float s = v.x*v.x + v.y*v.y + v.z*v.z + v.w*v.w;
    #pragma unroll
    for (int m = 32; m >= 1; m >>= 1) s += __shfl_xor(s, m);
    if (lane == 0) {
      if (isX) { xhalf[row] = 0.5f * s; rowkey[row] = 0xFFFFFFFFu; }
      else     { cbuf[r] = 0.5f * s - psi[r]; }
    }
  }
  if (blockIdx.x == 0 && threadIdx.x == 0) sum_accum[0] = 0.0f;
}

// stage fp8 B tile (128 col-rows x 256 B = 32 KB) for column-block t_ into half nb_.
// 4-bit XOR involution at 16B granularity: LDS[r][c16] = global[r][c16 ^ (r&15)].
#define STAGEB(t_, nb_) do {                                                    \
    _Pragma("unroll") for (int _g = 0; _g < 4; ++_g) {                          \
      const int _row = _g * 32 + wid * 4 + (lane >> 4);                         \
      const char* _src = (const char*)Yq + (size_t)((t_) * BN + _row) * 256     \
                         + ((((lane & 15) ^ (_row & 15)) << 4));                \
      __builtin_amdgcn_global_load_lds(                                         \
          (const __attribute__((address_space(1))) uint32_t*)_src,              \
          (__attribute__((address_space(3))) uint32_t*)                         \
              (ldsB + (nb_) * 32768 + (_g * 32 + wid * 4) * 256), 16, 0, 0);    \
    }                                                                           \
  } while (0)

// read this wave's 8 swizzled b128 fragments of tile buf_ into dst[2][2]
#define READB(dst, buf_) do {                                                   \
    const char* _bRd = ldsB + (buf_) * 32768;                                   \
    _Pragma("unroll") for (int _n = 0; _n < 2; ++_n)                            \
      _Pragma("unroll") for (int _kc = 0; _kc < 2; ++_kc) {                     \
        const int4v _lo = *(const int4v*)(_bRd + ((wc*32 + _n*16 + c15) << 8)   \
                          + (((_kc*8 + w4*2 + 0) ^ c15) << 4));                 \
        const int4v _hi = *(const int4v*)(_bRd + ((wc*32 + _n*16 + c15) << 8)   \
                          + (((_kc*8 + w4*2 + 1) ^ c15) << 4));                 \
        dst[_n][_kc] = (int8v){_lo[0],_lo[1],_lo[2],_lo[3],                     \
                               _hi[0],_hi[1],_hi[2],_hi[3]};                    \
      }                                                                         \
  } while (0)

// one pipelined iteration: MFMA on CUR (tile t_), prefetch NXT (tile t_+1),
// stage tile t_+2 into the LDS half CUR came from.
#define ITER(t_, CUR, NXT) do {                                                 \
    asm volatile("s_waitcnt lgkmcnt(0) vmcnt(0)" ::: "memory");                 \
    __builtin_amdgcn_s_barrier();                                               \
    if ((t_) + 2 < NT) STAGEB((t_) + 2, (t_) & 1);                              \
    if ((t_) + 1 < NT) READB(NXT, ((t_) + 1) & 1);                              \
    const float cj0 = Cs[(t_) * BN + wc * 32 +  0 + c15];                       \
    const float cj1 = Cs[(t_) * BN + wc * 32 + 16 + c15];                       \
    const f32x4 _z = {0.f, 0.f, 0.f, 0.f};                                      \
    f32x4 acc[4][2];                                                            \
    _Pragma("unroll") for (int _m = 0; _m < 4; ++_m) {                          \
      acc[_m][0] = _z; acc[_m][1] = _z;                                         \
    }                                                                           \
    __builtin_amdgcn_s_setprio(1);                                              \
    _Pragma("unroll") for (int _kc = 0; _kc < 2; ++_kc) {                       \
      _Pragma("unroll") for (int _m = 0; _m < 4; ++_m)                          \
        acc[_m][0] = __builtin_amdgcn_mfma_scale_f32_16x16x128_f8f6f4(          \
            a[_m][_kc], CUR[0][_kc], acc[_m][0], 0, 0, 0, 0x7F, 0, 0x7F);       \
      _Pragma("unroll") for (int _m = 0; _m < 4; ++_m)                          \
        acc[_m][1] = __builtin_amdgcn_mfma_scale_f32_16x16x128_f8f6f4(          \
            a[_m][_kc], CUR[1][_kc], acc[_m][1], 0, 0, 0, 0x7F, 0, 0x7F);       \
    }                                                                           \
    __builtin_amdgcn_s_setprio(0);                                              \
    const f32x4 _c0 = {cj0, cj0, cj0, cj0};                                     \
    const f32x4 _c1 = {cj1, cj1, cj1, cj1};                                     \
    _Pragma("unroll") for (int _m = 0; _m < 4; ++_m)                            \
      vmin[_m] = vmin4(vmin[_m], vmin4(_c0 - acc[_m][0], _c1 - acc[_m][1]));    \
  } while (0)

// ---- K2: persistent-row MX-fp8 MFMA sweep; A (64 rows x K=256) in registers;
//          B via double-buffered swizzled LDS; B FRAGMENTS double-buffered in
//          registers, skewed one tile -> ds_read/stage overlap MFMA.
__global__ __attribute__((amdgpu_flat_work_group_size(512, 512),
                          amdgpu_waves_per_eu(2, 2)))
void k_gemm(const uint32_t* __restrict__ Xq, const uint32_t* __restrict__ Yq,
            const float* __restrict__ cbuf, uint32_t* __restrict__ rowkey)
{
  __shared__ __align__(16) char shm[2 * 32768 + 32768];  // 2 B-halves + Cs
  char* ldsB = shm;
  const float* Cs = (const float*)(shm + 65536);

  const int brow = blockIdx.x * BM;
  const int tid  = threadIdx.x;
  const int wid  = tid >> 6;
  const int lane = tid & 63;
  const int wr = wid >> 2;          // 0..1 -> rows wr*64
  const int wc = wid & 3;           // 0..3 -> cols wc*32 within BN
  const int c15 = lane & 15;
  const int w4  = lane >> 4;

  // A fragments -> registers: 8 x 32B = 64 VGPRs per lane.
  int8v a[4][2];
  {
    const char* aBase = (const char*)Xq + ((size_t)(brow + wr * 64 + c15) << 8) + w4 * 32;
    #pragma unroll
    for (int m = 0; m < 4; ++m)
      #pragma unroll
      for (int kc = 0; kc < 2; ++kc)
        a[m][kc] = *(const int8v*)(aBase + m * 16 * 256 + kc * 128);
  }

  // stage Cs (32 KB of cbuf) + tile 0
  #pragma unroll
  for (int g = 0; g < 4; ++g)
    __builtin_amdgcn_global_load_lds(
        (const __attribute__((address_space(1))) uint32_t*)((const char*)cbuf + (g * 512 + tid) * 16),
        (__attribute__((address_space(3))) uint32_t*)(shm + 65536 + g * 8192 + wid * 1024),
        16, 0, 0);
  STAGEB(0, 0);
  asm volatile("s_waitcnt vmcnt(0)" ::: "memory");
  __builtin_amdgcn_s_barrier();

  int8v bfA[2][2], bfB[2][2];
  READB(bfA, 0);        // tile-0 fragments in flight
  STAGEB(1, 1);         // tile-1 staging in flight

  f32x4 vmin[4];
  #pragma unroll
  for (int m = 0; m < 4; ++m)
    vmin[m] = (f32x4){3.4e38f, 3.4e38f, 3.4e38f, 3.4e38f};

  #pragma unroll 1
  for (int tt = 0; tt < NT; tt += 2) {
    ITER(tt,     bfA, bfB);
    ITER(tt + 1, bfB, bfA);
  }

  // epilogue: reduce min across the 16 lanes of each column group, then atomicMin.
  // C/D layout (shape-determined): col = lane&15, row = (lane>>4)*4 + reg
  #pragma unroll
  for (int m = 0; m < 4; ++m) {
    #pragma unroll
    for (int r = 0; r < 4; ++r) {
      float v = vmin[m][r];
      v = fminf(v, __shfl_xor(v, 1));
      v = fminf(v, __shfl_xor(v, 2));
      v = fminf(v, __shfl_xor(v, 4));
      v = fminf(v, __shfl_xor(v, 8));
      vmin[m][r] = v;
    }
    if (c15 < 4) {
      float vsel = vmin[m][0];
      vsel = (c15 == 1) ? vmin[m][1] : vsel;
      vsel = (c15 == 2) ? vmin[m][2] : vsel;
      vsel = (c15 == 3) ? vmin[m][3] : vsel;
      const int row = brow + wr * 64 + m * 16 + w4 * 4 + c15;
      atomicMin((unsigned int*)&rowkey[row], fkey(vsel));
    }
  }
}

// ---- K3: sum over rows of (min + 0.5||x||^2)
__global__ void k_rowred(const float* __restrict__ xhalf, const uint32_t* __restrict__ rowkey,
                         float* __restrict__ sum_accum)
{
  __shared__ float sh[4];
  const int i = blockIdx.x * 256 + threadIdx.x;
  float v = funkey(rowkey[i]) + xhalf[i];
  #pragma unroll
  for (int m = 32; m >= 1; m >>= 1) v += __shfl_xor(v, m);
  const int wid = threadIdx.x >> 6, lane = threadIdx.x & 63;
  if (lane == 0) sh[wid] = v;
  __syncthreads();
  if (threadIdx.x == 0) atomicAdd(sum_accum, sh[0] + sh[1] + sh[2] + sh[3]);
}

// ---- K4: out = sum/N + mean(psi)
__global__ void k_final(const float* __restrict__ psi, const float* __restrict__ sum_accum,
                        float* __restrict__ out)
{
  __shared__ float sh[4];
  float s = 0.f;
  for (int i = threadIdx.x; i < MCOLS; i += 256) s += psi[i];
  #pragma unroll
  for (int m = 32; m >= 1; m >>= 1) s += __shfl_xor(s, m);
  const int wid = threadIdx.x >> 6, lane = threadIdx.x & 63;
  if (lane == 0) sh[wid] = s;
  __syncthreads();
  if (threadIdx.x == 0)
    out[0] = sum_accum[0] / (float)NROWS + (sh[0] + sh[1] + sh[2] + sh[3]) / (float)MCOLS;
}

extern "C" void kernel_launch(void* const* d_in, const int* in_sizes, int n_in,
                              void* d_out, int out_size, void* d_ws, size_t ws_size,
                              hipStream_t stream)
{
  const float* X   = (const float*)d_in[0];
  const float* Y   = (const float*)d_in[1];
  const float* psi = (const float*)d_in[2];
  float* out = (float*)d_out;

  char* ws = (char*)d_ws;
  uint32_t* Xq     = (uint32_t*)(ws);                                           // 8,388,608 B
  uint32_t* Yq     = (uint32_t*)(ws + (size_t)NROWS * DDIM);                    // 2,097,152 B
  float* cbuf      = (float*)(ws + (size_t)(NROWS + MCOLS) * DDIM);             //    32,768 B
  uint32_t* rowkey = (uint32_t*)((char*)cbuf + (size_t)MCOLS * 4);              //   131,072 B
  float* xhalf     = (float*)((char*)rowkey + (size_t)NROWS * 4);               //   131,072 B
  float* sum_accum = (float*)((char*)xhalf + (size_t)NROWS * 4);                //         4 B

  k_prep  <<<2048, 256, 0, stream>>>(X, Y, psi, Xq, Yq, xhalf, cbuf, rowkey, sum_accum);
  k_gemm  <<<NWG, 512, 0, stream>>>(Xq, Yq, cbuf, rowkey);
  k_rowred<<<NROWS / 256, 256, 0, stream>>>(xhalf, rowkey, sum_accum);
  k_final <<<1, 256, 0, stream>>>(psi, sum_accum, out);
}